// Round 12
// baseline (56.089 us; speedup 1.0000x reference)
//
#include <hip/hip_runtime.h>

// PDF sampler (NeRF sample_pdf): one 64-lane wave per ray.
// R11 = R10 (best: 54.1us) with ONE variable: kWaves 4 -> 2.
// Gradient confirmed R6->R10 (8->4 waves: 55.7->54.1): the block barrier gates
// writeback on the slowest coupled wave; width 2 halves straggler skew again
// and gives 16 independent 128-thread blocks/CU (same 32 waves/CU).
// All load-bearing components byte-identical (R7/R8/R9 proved them):
//  - DPP wave64 inclusive scan (row_shr 1/2/4/8 + row_bcast 15/31): pure VALU.
//  - u_j=(j+0.5)/129 uniform & sorted -> lane's cdf interval [c0,c1) owns the
//    contiguous sample range [js, js_next): O(1) estimate + 1 fixup, no search.
//  - sort(concat(exist,new)) closed-form ranks: sample j (interval k=lane+1)
//    -> rank j+k ; exist[lane] -> rank lane+js ; exist[64]=max_bin -> rank 193
//    = the dropped element. No sort, no search.
//  - Scatter rows in LDS; block writes its rays' 1544 B contiguously as 96
//    aligned nontemporal dwordx4 stores + one 8 B tail (R4: kills write
//    amplification; R6: nt keeps the 202 MB output stream out of L2/L3).

constexpr int kNCoarse = 64;            // coarse bins per ray (== wave size)
constexpr int kNumU    = 129;           // NUM_SAMPLES + 1
constexpr int kNOut    = 193;           // output samples per ray
constexpr int kWaves   = 2;             // rays per block  (R11 single variable)
constexpr int kBlock   = kWaves * 64;   // 128 threads
constexpr int kBlockF  = kWaves * kNOut;   // 386 floats staged per block
constexpr int kBlockV4 = kBlockF / 4;      // 96 full float4 stores (+2-float tail)

typedef float f32x4 __attribute__((ext_vector_type(4)));   // native vector for nt-store

// DPP update: lanes receive src per ctrl; invalid lanes keep oldv (bctrl=false) or 0 (true).
#define DPP_UPD_F(oldv, srcv, ctrl, rmask, bctrl)                             \
  __int_as_float(__builtin_amdgcn_update_dpp(                                 \
      __float_as_int(oldv), __float_as_int(srcv), (ctrl), (rmask), 0xF, (bctrl)))

__global__ __launch_bounds__(kBlock) void pdf_sampler_kernel(
    const float* __restrict__ weights,
    const float* __restrict__ bins,
    const float* __restrict__ max_bin,
    float* __restrict__ out,
    int n_rays)
{
    const int tid  = threadIdx.x;
    const int lane = tid & 63;
    const int wid  = tid >> 6;
    const int ray  = blockIdx.x * kWaves + wid;

    __shared__ __align__(16) float s_m[kBlockF];

    if (ray < n_rays) {
        // ---- loads (coalesced 256 B/wave; max_bin wave-uniform) ----
        const float w  = weights[(size_t)ray * kNCoarse + lane] + 0.01f;  // HIST_PAD
        const float b0 = bins[(size_t)ray * kNCoarse + lane];
        const float mb = max_bin[ray];

        // ---- wave64 inclusive scan of w via DPP (6 VALU ops) ----
        float c = w;
        c += DPP_UPD_F(0.0f, c, 0x111, 0xF, true);   // row_shr:1
        c += DPP_UPD_F(0.0f, c, 0x112, 0xF, true);   // row_shr:2
        c += DPP_UPD_F(0.0f, c, 0x114, 0xF, true);   // row_shr:4
        c += DPP_UPD_F(0.0f, c, 0x118, 0xF, true);   // row_shr:8
        c += DPP_UPD_F(0.0f, c, 0x142, 0xA, false);  // row_bcast:15 -> rows 1,3
        c += DPP_UPD_F(0.0f, c, 0x143, 0xC, false);  // row_bcast:31 -> rows 2,3

        const float ws        = __int_as_float(__builtin_amdgcn_readlane(__float_as_int(c), 63));
        const float padding   = fmaxf(1e-5f - ws, 0.0f);     // EPS pad (0 for these inputs)
        const float inv_total = __builtin_amdgcn_rcpf(ws + padding);  // ~1ulp, thr=0.098
        const float pad64     = padding * (1.0f / 64.0f);

        const float c1 = fminf((c + (float)(lane + 1) * pad64) * inv_total, 1.0f); // cdf[lane+1]
        const float c0 = DPP_UPD_F(0.0f, c1, 0x138, 0xF, true);   // wf_sr:1 -> cdf[lane]
        const float b1 = DPP_UPD_F(mb,   b0, 0x130, 0xF, false);  // wf_sl:1 -> exist[lane+1]

        // ---- js = min{j : u_j >= c0}: estimate + one branchless fixup ----
        const float kInv = 1.0f / 129.0f, kHalf = 0.5f / 129.0f;
        int js = (int)ceilf(fmaf(c0, 129.0f, -0.5f));
        js = min(max(js, 0), kNumU);
        {
            const float um1 = fmaf((float)(js - 1), kInv, kHalf);
            const float u0e = fmaf((float)js,       kInv, kHalf);
            if (js > 0 && um1 >= c0)           js -= 1;
            else if (js < kNumU && u0e < c0)   js += 1;
        }
        const int js_next = __builtin_amdgcn_update_dpp(kNumU, js, 0x130, 0xF, 0xF, false);

        // ---- interpolation as arithmetic sequence over this lane's samples ----
        const float denom  = c1 - c0;
        const float rdenom = (denom > 0.0f) ? __builtin_amdgcn_rcpf(denom) : 0.0f;
        const float dbin   = b1 - b0;
        const float u0     = fmaf((float)js, kInv, kHalf);
        const float t0     = fminf(fmaxf((u0 - c0) * rdenom, 0.0f), 1.0f);
        float       val    = fmaf(t0, dbin, b0);
        const float step   = kInv * rdenom * dbin;

        // ---- scatter into this ray's LDS row at exact merged ranks (R6 form) ----
        float* mrow = s_m + wid * kNOut;
        mrow[lane + js] = b0;                       // exist[lane] at rank lane+js (<=192)
        for (int j = js; j < js_next; ++j) {        // samples at ranks j+lane+1
            mrow[j + lane + 1] = val;
            val += step;
        }
    }

    __syncthreads();   // drains LDS writes (compiler emits lgkmcnt(0) before barrier)

    // ---- block-wide coalesced writeback, non-temporal (don't pollute L2/L3) ----
    {
        const int raysHere = min(n_rays - blockIdx.x * kWaves, kWaves);
        if (raysHere > 0) {
            const int nf = raysHere * kNOut;          // 193 or 386
            float* obase = out + (size_t)blockIdx.x * kBlockF;
            if (tid <= kBlockV4) {                    // 96 full float4 + tail thread
                const int off = tid * 4;
                if (off + 3 < nf) {
                    const f32x4 v = *reinterpret_cast<const f32x4*>(&s_m[off]);
                    __builtin_nontemporal_store(v, reinterpret_cast<f32x4*>(&obase[off]));
                } else {
                    for (int k = off; k < nf; ++k)
                        __builtin_nontemporal_store(s_m[k], &obase[k]);  // <=3 tail elems
                }
            }
        }
    }
}

extern "C" void kernel_launch(void* const* d_in, const int* in_sizes, int n_in,
                              void* d_out, int out_size, void* d_ws, size_t ws_size,
                              hipStream_t stream) {
    const float* weights = (const float*)d_in[0];
    const float* bins    = (const float*)d_in[1];
    const float* max_bin = (const float*)d_in[2];
    float* out = (float*)d_out;
    const int n_rays = in_sizes[2];  // one max_bin entry per ray
    const int blocks = (n_rays + kWaves - 1) / kWaves;
    pdf_sampler_kernel<<<blocks, kBlock, 0, stream>>>(weights, bins, max_bin, out, n_rays);
}

// Round 13
// 53.942 us; speedup vs baseline: 1.0398x; 1.0398x over previous
//
#include <hip/hip_runtime.h>

// PDF sampler (NeRF sample_pdf): one 64-lane wave per ray.
// R12 = R10 revert (best: 54.1us). Axis search complete:
//   kWaves: 8 -> 55.7 | 4 -> 54.1 (BEST) | 2 -> 56.1
//   R7 block pipeline: regressed. R8 per-ray writeback: regressed.
//   R9 paired ds_write2: regressed. R3 direct scattered stores: regressed.
// Load-bearing structure (each validated by a failed perturbation):
//  - DPP wave64 inclusive scan (row_shr 1/2/4/8 + row_bcast 15/31): pure VALU.
//  - u_j=(j+0.5)/129 uniform & sorted -> lane's cdf interval [c0,c1) owns the
//    contiguous sample range [js, js_next): O(1) estimate + 1 fixup, no search.
//  - sort(concat(exist,new)) closed-form ranks: sample j (interval k=lane+1)
//    -> rank j+k ; exist[lane] -> rank lane+js ; exist[64]=max_bin -> rank 193
//    = the dropped element. No sort, no search.
//  - Scatter rows in LDS; block writes its rays' 3088 B contiguously as 193
//    aligned nontemporal dwordx4 stores (R4: kills write amplification;
//    R6: nt keeps the 202 MB output stream from evicting L3-resident inputs).

constexpr int kNCoarse = 64;            // coarse bins per ray (== wave size)
constexpr int kNumU    = 129;           // NUM_SAMPLES + 1
constexpr int kNOut    = 193;           // output samples per ray
constexpr int kWaves   = 4;             // rays per block  (optimum, R10)
constexpr int kBlock   = kWaves * 64;   // 256 threads
constexpr int kBlockF  = kWaves * kNOut;   // 772 floats staged per block
constexpr int kBlockV4 = kBlockF / 4;      // 193 float4 stores per block

typedef float f32x4 __attribute__((ext_vector_type(4)));   // native vector for nt-store

// DPP update: lanes receive src per ctrl; invalid lanes keep oldv (bctrl=false) or 0 (true).
#define DPP_UPD_F(oldv, srcv, ctrl, rmask, bctrl)                             \
  __int_as_float(__builtin_amdgcn_update_dpp(                                 \
      __float_as_int(oldv), __float_as_int(srcv), (ctrl), (rmask), 0xF, (bctrl)))

__global__ __launch_bounds__(kBlock) void pdf_sampler_kernel(
    const float* __restrict__ weights,
    const float* __restrict__ bins,
    const float* __restrict__ max_bin,
    float* __restrict__ out,
    int n_rays)
{
    const int tid  = threadIdx.x;
    const int lane = tid & 63;
    const int wid  = tid >> 6;
    const int ray  = blockIdx.x * kWaves + wid;

    __shared__ __align__(16) float s_m[kBlockF];

    if (ray < n_rays) {
        // ---- loads (coalesced 256 B/wave; max_bin wave-uniform) ----
        const float w  = weights[(size_t)ray * kNCoarse + lane] + 0.01f;  // HIST_PAD
        const float b0 = bins[(size_t)ray * kNCoarse + lane];
        const float mb = max_bin[ray];

        // ---- wave64 inclusive scan of w via DPP (6 VALU ops) ----
        float c = w;
        c += DPP_UPD_F(0.0f, c, 0x111, 0xF, true);   // row_shr:1
        c += DPP_UPD_F(0.0f, c, 0x112, 0xF, true);   // row_shr:2
        c += DPP_UPD_F(0.0f, c, 0x114, 0xF, true);   // row_shr:4
        c += DPP_UPD_F(0.0f, c, 0x118, 0xF, true);   // row_shr:8
        c += DPP_UPD_F(0.0f, c, 0x142, 0xA, false);  // row_bcast:15 -> rows 1,3
        c += DPP_UPD_F(0.0f, c, 0x143, 0xC, false);  // row_bcast:31 -> rows 2,3

        const float ws        = __int_as_float(__builtin_amdgcn_readlane(__float_as_int(c), 63));
        const float padding   = fmaxf(1e-5f - ws, 0.0f);     // EPS pad (0 for these inputs)
        const float inv_total = __builtin_amdgcn_rcpf(ws + padding);  // ~1ulp, thr=0.098
        const float pad64     = padding * (1.0f / 64.0f);

        const float c1 = fminf((c + (float)(lane + 1) * pad64) * inv_total, 1.0f); // cdf[lane+1]
        const float c0 = DPP_UPD_F(0.0f, c1, 0x138, 0xF, true);   // wf_sr:1 -> cdf[lane]
        const float b1 = DPP_UPD_F(mb,   b0, 0x130, 0xF, false);  // wf_sl:1 -> exist[lane+1]

        // ---- js = min{j : u_j >= c0}: estimate + one branchless fixup ----
        const float kInv = 1.0f / 129.0f, kHalf = 0.5f / 129.0f;
        int js = (int)ceilf(fmaf(c0, 129.0f, -0.5f));
        js = min(max(js, 0), kNumU);
        {
            const float um1 = fmaf((float)(js - 1), kInv, kHalf);
            const float u0e = fmaf((float)js,       kInv, kHalf);
            if (js > 0 && um1 >= c0)           js -= 1;
            else if (js < kNumU && u0e < c0)   js += 1;
        }
        const int js_next = __builtin_amdgcn_update_dpp(kNumU, js, 0x130, 0xF, 0xF, false);

        // ---- interpolation as arithmetic sequence over this lane's samples ----
        const float denom  = c1 - c0;
        const float rdenom = (denom > 0.0f) ? __builtin_amdgcn_rcpf(denom) : 0.0f;
        const float dbin   = b1 - b0;
        const float u0     = fmaf((float)js, kInv, kHalf);
        const float t0     = fminf(fmaxf((u0 - c0) * rdenom, 0.0f), 1.0f);
        float       val    = fmaf(t0, dbin, b0);
        const float step   = kInv * rdenom * dbin;

        // ---- scatter into this ray's LDS row at exact merged ranks (R6 form) ----
        float* mrow = s_m + wid * kNOut;
        mrow[lane + js] = b0;                       // exist[lane] at rank lane+js (<=192)
        for (int j = js; j < js_next; ++j) {        // samples at ranks j+lane+1
            mrow[j + lane + 1] = val;
            val += step;
        }
    }

    __syncthreads();   // drains LDS writes (compiler emits lgkmcnt(0) before barrier)

    // ---- block-wide coalesced writeback, non-temporal (don't pollute L2/L3) ----
    {
        const int raysHere = min(n_rays - blockIdx.x * kWaves, kWaves);
        if (raysHere > 0) {
            const int nf = raysHere * kNOut;
            float* obase = out + (size_t)blockIdx.x * kBlockF;
            if (tid < kBlockV4) {
                const int off = tid * 4;
                if (off + 3 < nf) {
                    const f32x4 v = *reinterpret_cast<const f32x4*>(&s_m[off]);
                    __builtin_nontemporal_store(v, reinterpret_cast<f32x4*>(&obase[off]));
                } else {
                    for (int k = off; k < nf; ++k)
                        __builtin_nontemporal_store(s_m[k], &obase[k]);  // <=3 tail elems
                }
            }
        }
    }
}

extern "C" void kernel_launch(void* const* d_in, const int* in_sizes, int n_in,
                              void* d_out, int out_size, void* d_ws, size_t ws_size,
                              hipStream_t stream) {
    const float* weights = (const float*)d_in[0];
    const float* bins    = (const float*)d_in[1];
    const float* max_bin = (const float*)d_in[2];
    float* out = (float*)d_out;
    const int n_rays = in_sizes[2];  // one max_bin entry per ray
    const int blocks = (n_rays + kWaves - 1) / kWaves;
    pdf_sampler_kernel<<<blocks, kBlock, 0, stream>>>(weights, bins, max_bin, out, n_rays);
}